// Round 7
// baseline (418.357 us; speedup 1.0000x reference)
//
#include <hip/hip_runtime.h>
#include <hip/hip_bf16.h>
#include <math.h>

// Problem constants (from reference: BSZ, L, D, K = 4, 4096, 512, 4)
#define BSZ   4
#define LSEQ  4096
#define DDIM  512
#define KBAND 4
#define MROWS (BSZ*LSEQ)          // 16384
#define BLD   (MROWS*DDIM)        // 8388608
#define CHUNK 16
#define NCH   (LSEQ/CHUNK)        // 256
#define NGRP  16                  // groups of 16 chunks
#define TBL   ((CHUNK+1)*DDIM)    // 17*512 a^k table entries
#define NCOLS 2048                // 2*(2*D) GEMM output columns

typedef __attribute__((ext_vector_type(8))) short  short8;
typedef __attribute__((ext_vector_type(8))) unsigned short u16x8;
typedef __attribute__((ext_vector_type(4))) unsigned short u16x4;
typedef __attribute__((ext_vector_type(4))) float  f32x4;

__device__ __forceinline__ unsigned short f2bf(float f) {
    unsigned int u = __float_as_uint(f);
    u = (u + 0x7FFFu + ((u >> 16) & 1u)) >> 16;
    return (unsigned short)u;
}
__device__ __forceinline__ float bf2f(unsigned short h) {
    return __uint_as_float(((unsigned int)h) << 16);
}

__device__ __forceinline__ void gld_lds16(const void* g, void* l) {
    __builtin_amdgcn_global_load_lds(
        (const __attribute__((address_space(1))) void*)g,
        (__attribute__((address_space(3))) void*)l, 16, 0, 0);
}

// ---------------------------------------------------------------------------
// Kernel 1: tables — ap[k]=a^k (k=0..16), apg[k]=a^(16k) (k=0..16), band maps
// ---------------------------------------------------------------------------
__global__ void k_prep(const float* __restrict__ omega,
                       const float* __restrict__ log_gamma,
                       const float* __restrict__ dt,
                       const int*   __restrict__ band_idx,
                       float* __restrict__ apR, float* __restrict__ apI,
                       float* __restrict__ apgR, float* __restrict__ apgI,
                       int* __restrict__ bandOf, int* __restrict__ posOf)
{
    int gid = blockIdx.x * blockDim.x + threadIdx.x;
    float dta = fabsf(dt[0]);
    if (gid < TBL) {
        int k = gid / DDIM, d = gid % DDIM;
        float g = -expf(log_gamma[d]);
        float w = omega[d];
        float e = expf(g * dta * (float)k);
        float s, c;
        sincosf(w * dta * (float)k, &s, &c);
        apR[gid] = e * c;
        apI[gid] = e * s;
    } else if (gid < 2*TBL) {
        int gg = gid - TBL;
        int k = gg / DDIM, d = gg % DDIM;
        float g = -expf(log_gamma[d]);
        float w = omega[d];
        float ph = dta * (float)(16 * k);
        float e = expf(g * ph);
        float s, c;
        sincosf(w * ph, &s, &c);
        apgR[gg] = e * c;
        apgI[gg] = e * s;
    }
    if (gid < DDIM) {
        int d = band_idx[gid];              // gid = k*128 + j
        bandOf[d] = gid >> 7;
        posOf[d]  = gid & 127;
    }
}

// ---------------------------------------------------------------------------
// Kernel 2: FUSED gate + A-conversion (unchanged from round 5)
// ---------------------------------------------------------------------------
__global__ void k_cvtgate(const float* __restrict__ x,
                          const float* __restrict__ z_prev,
                          const float* __restrict__ Wg,
                          const float* __restrict__ bg,
                          const float* __restrict__ sg,
                          float* __restrict__ gate,
                          unsigned short* __restrict__ Ahi,
                          unsigned short* __restrict__ Alo)
{
    int m    = blockIdx.x * 4 + (threadIdx.x >> 6);
    int lane = threadIdx.x & 63;
    const float4* xr = (const float4*)(x      + ((size_t)m << 9));
    const float4* zr = (const float4*)(z_prev + ((size_t)m << 9));
    const float4* wg = (const float4*)Wg;
    float dot = 0.f, sur = 0.f;
    int msw = m & 7;
#pragma unroll
    for (int i = 0; i < 2; i++) {
        int e = lane + i*64;               // float4 index 0..127
        float4 a = xr[e];
        float4 z = zr[e];
        float4 w = wg[e];
        dot += a.x*w.x + a.y*w.y + a.z*w.z + a.w*w.w;
        sur += fabsf(a.x-z.x) + fabsf(a.y-z.y) + fabsf(a.z-z.z) + fabsf(a.w-z.w);
        float fa[4] = {a.x, a.y, a.z, a.w};
        u16x4 h, l;
#pragma unroll
        for (int j = 0; j < 4; ++j) {
            unsigned short hb = f2bf(fa[j]);
            h[j] = hb;
            l[j] = f2bf(fa[j] - bf2f(hb));
        }
        int grp = e >> 1, half = e & 1;
        int chunk = grp >> 3, gs = grp & 7;
        int gd = gs ^ msw;
        size_t dst = ((size_t)m << 9) + chunk*64 + gd*8 + half*4;
        *(u16x4*)(Ahi + dst) = h;
        *(u16x4*)(Alo + dst) = l;
    }
#pragma unroll
    for (int mm = 32; mm; mm >>= 1) { dot += __shfl_xor(dot, mm); sur += __shfl_xor(sur, mm); }
    if (lane == 0) {
        float g = 1.f / (1.f + expf(-(dot + bg[0])));
        g *= (1.f + tanhf(sg[0]) * (sur * (1.f/512.f)));
        gate[m] = g;
    }
}

// ---------------------------------------------------------------------------
// Kernel 3: convert W -> bf16 hi/lo planes, pre-swizzled (unchanged)
// ---------------------------------------------------------------------------
__global__ void k_cvtB(const float* __restrict__ Wpsi,
                       const float* __restrict__ Wphi,
                       unsigned short* __restrict__ Bhi,
                       unsigned short* __restrict__ Blo)
{
    int gid = blockIdx.x * 256 + threadIdx.x;   // NCOLS*64 threads
    int n = gid >> 6, grp = gid & 63;
    int chunk = grp >> 3, g = grp & 7;
    int se = chunk*64 + ((g ^ (n & 7)) << 3);
    const float* wp = (n < 1024) ? (Wpsi + ((size_t)n << 9) + se)
                                 : (Wphi + ((size_t)(n - 1024) << 9) + se);
    u16x8 h, l;
#pragma unroll
    for (int j = 0; j < 8; ++j) {
        float f = wp[j];
        unsigned short hb = f2bf(f);
        h[j] = hb;
        l[j] = f2bf(f - bf2f(hb));
    }
    size_t dst = ((size_t)n << 9) + grp*8;
    *(u16x8*)(Bhi + dst) = h;
    *(u16x8*)(Blo + dst) = l;
}

// ---------------------------------------------------------------------------
// Kernel 4: bf16 MFMA GEMM, 3-term split precision (byte-identical, verified)
// ---------------------------------------------------------------------------
__global__ __launch_bounds__(256)
void k_gemm_bf16(const unsigned short* __restrict__ Ahi,
                 const unsigned short* __restrict__ Alo,
                 const unsigned short* __restrict__ Bhi,
                 const unsigned short* __restrict__ Blo,
                 const float* __restrict__ bpsi, const float* __restrict__ bphi,
                 float* __restrict__ psiR, float* __restrict__ psiI,
                 float* __restrict__ phiR, float* __restrict__ phiI)
{
    __shared__ __align__(16) char As[16384];
    __shared__ __align__(16) char Bs[16384];

    int bid = blockIdx.x;
    int wg  = (bid & 7) * 256 + (bid >> 3);   // XCD swizzle, nwg=2048 (%8==0)
    int m0 = (wg >> 4) * 128;
    int n0 = (wg & 15) * 128;

    int tid  = threadIdx.x;
    int lane = tid & 63;
    int wv   = tid >> 6;
    int wm = wv >> 1, wn = wv & 1;
    int lr = lane & 15, lk = lane >> 4;

    f32x4 acc[4][4];
#pragma unroll
    for (int mi = 0; mi < 4; ++mi)
#pragma unroll
        for (int ni = 0; ni < 4; ++ni) acc[mi][ni] = (f32x4)0.f;

    for (int s = 0; s < 24; ++s) {
        const unsigned short* Asrc = (s >= 8 && s < 16) ? Alo : Ahi;
        const unsigned short* Bsrc = (s < 16) ? Bhi : Blo;
        int kb2 = (s & 7) << 7;

        __syncthreads();
#pragma unroll
        for (int i = 0; i < 4; ++i) {
            int flat = tid + i * 256;
            int r = flat >> 3, g = flat & 7;
            size_t goff = ((size_t)r << 10) + kb2 + g * 16;
            gld_lds16((const char*)Asrc + ((size_t)m0 << 10) + goff,
                      As + (wv * 64 + i * 256) * 16);
            gld_lds16((const char*)Bsrc + ((size_t)n0 << 10) + goff,
                      Bs + (wv * 64 + i * 256) * 16);
        }
        __syncthreads();

#pragma unroll
        for (int kk = 0; kk < 2; ++kk) {
            int tb = (kk * 64 + lk * 16) ^ ((lr & 7) << 4);
            short8 af[4], bfr[4];
#pragma unroll
            for (int mi = 0; mi < 4; ++mi) {
                int r = wm * 64 + mi * 16 + lr;
                af[mi] = *(const short8*)(As + r * 128 + tb);
            }
#pragma unroll
            for (int ni = 0; ni < 4; ++ni) {
                int r = wn * 64 + ni * 16 + lr;
                bfr[ni] = *(const short8*)(Bs + r * 128 + tb);
            }
#pragma unroll
            for (int mi = 0; mi < 4; ++mi)
#pragma unroll
                for (int ni = 0; ni < 4; ++ni)
                    acc[mi][ni] = __builtin_amdgcn_mfma_f32_16x16x32_bf16(
                        af[mi], bfr[ni], acc[mi][ni], 0, 0, 0);
        }
    }

#pragma unroll
    for (int ni = 0; ni < 4; ++ni) {
        int ncol = n0 + wn * 64 + ni * 16 + lr;
        float bias = (ncol < 1024) ? bpsi[ncol] : bphi[ncol - 1024];
        int p = ncol >> 9;
        float* plane = (p == 0) ? psiR : (p == 1) ? psiI : (p == 2) ? phiR : phiI;
        int col = ncol & 511;
#pragma unroll
        for (int mi = 0; mi < 4; ++mi) {
            int mrow = m0 + wm * 64 + mi * 16 + lk * 4;
#pragma unroll
            for (int j = 0; j < 4; ++j)
                plane[(size_t)(mrow + j) * 512 + col] = acc[mi][ni][j] + bias;
        }
    }
}

// ---------------------------------------------------------------------------
// Kernel 5: chunked local scan — REGISTER-PRELOAD version.
// All 32 U loads issue before the recurrence; stores after. Breaks any
// load-after-store serialization of the in-place RMW.
// ---------------------------------------------------------------------------
__launch_bounds__(512)
__global__ void k_scan(float* __restrict__ HR, float* __restrict__ HI,
                       const float* __restrict__ gate,
                       const float* __restrict__ Bvec,
                       const float* __restrict__ apR, const float* __restrict__ apI,
                       float* __restrict__ carR, float* __restrict__ carI)
{
    int b = blockIdx.x >> 8;       // NCH = 256
    int c = blockIdx.x & 255;
    int d = threadIdx.x;
    float ar = apR[DDIM + d], ai = apI[DDIM + d];   // a^1
    float bv = Bvec[d];
    int t0 = c * CHUNK;
    size_t base = ((size_t)b * LSEQ + t0) * DDIM + d;
    const float* grow = gate + (size_t)b * LSEQ + t0;

    float ur[CHUNK], ui[CHUNK];
#pragma unroll
    for (int t = 0; t < CHUNK; t++) {
        ur[t] = HR[base + (size_t)t * DDIM];
        ui[t] = HI[base + (size_t)t * DDIM];
    }
    float hr = 0.f, hi = 0.f;
#pragma unroll
    for (int t = 0; t < CHUNK; t++) {
        float g  = grow[t] * bv;               // grow[t] is wave-uniform
        float nr = ar*hr - ai*hi + g * ur[t];
        float ni = ar*hi + ai*hr + g * ui[t];
        hr = nr; hi = ni;
        ur[t] = hr; ui[t] = hi;
    }
#pragma unroll
    for (int t = 0; t < CHUNK; t++) {
        HR[base + (size_t)t * DDIM] = ur[t];
        HI[base + (size_t)t * DDIM] = ui[t];
    }
    size_t ci = ((size_t)(b * NCH + c)) * DDIM + d;
    carR[ci] = hr; carI[ci] = hi;
}

// ---------------------------------------------------------------------------
// Kernel 6a: within-group inclusive scan of chunk carries — preload version
// ---------------------------------------------------------------------------
__global__ void k_carryA(float* __restrict__ carR, float* __restrict__ carI,
                         const float* __restrict__ apR, const float* __restrict__ apI)
{
    int gid = blockIdx.x * 256 + threadIdx.x;   // BSZ*NGRP*DDIM
    int d = gid & 511, cg = (gid >> 9) & 15, b = gid >> 13;
    float qr = apR[CHUNK*DDIM + d], qi = apI[CHUNK*DDIM + d];  // a^16
    size_t i0 = ((size_t)(b * NCH + cg * 16)) * DDIM + d;
    float xr[15], xi[15];
#pragma unroll
    for (int j = 1; j < 16; j++) {
        xr[j-1] = carR[i0 + (size_t)j * DDIM];
        xi[j-1] = carI[i0 + (size_t)j * DDIM];
    }
    float cr = carR[i0], ci = carI[i0];
#pragma unroll
    for (int j = 1; j < 16; j++) {
        float nr = qr*cr - qi*ci + xr[j-1];
        float ni = qr*ci + qi*cr + xi[j-1];
        cr = nr; ci = ni;
        xr[j-1] = cr; xi[j-1] = ci;
    }
#pragma unroll
    for (int j = 1; j < 16; j++) {
        carR[i0 + (size_t)j * DDIM] = xr[j-1];
        carI[i0 + (size_t)j * DDIM] = xi[j-1];
    }
}

// ---------------------------------------------------------------------------
// Kernel 6b: combine group totals — preload version
// ---------------------------------------------------------------------------
__global__ void k_carryB(const float* __restrict__ carR, const float* __restrict__ carI,
                         const float* __restrict__ apgR, const float* __restrict__ apgI,
                         float* __restrict__ gcarR, float* __restrict__ gcarI)
{
    int gid = blockIdx.x * 256 + threadIdx.x;   // BSZ*DDIM = 2048
    int d = gid & 511, b = gid >> 9;
    float Qr = apgR[16*DDIM + d], Qi = apgI[16*DDIM + d];      // a^256
    float tr[NGRP], ti[NGRP];
#pragma unroll
    for (int cg = 0; cg < NGRP; cg++) {
        size_t idx = ((size_t)(b * NCH + cg*16 + 15)) * DDIM + d;
        tr[cg] = carR[idx]; ti[cg] = carI[idx];
    }
    float gr = tr[0], gi = ti[0];
    gcarR[((size_t)(b*NGRP))*DDIM + d] = gr;
    gcarI[((size_t)(b*NGRP))*DDIM + d] = gi;
#pragma unroll
    for (int cg = 1; cg < NGRP; cg++) {
        float nr = Qr*gr - Qi*gi + tr[cg];
        float ni = Qr*gi + Qi*gr + ti[cg];
        gr = nr; gi = ni;
        gcarR[((size_t)(b*NGRP + cg))*DDIM + d] = gr;
        gcarI[((size_t)(b*NGRP + cg))*DDIM + d] = gi;
    }
}

// ---------------------------------------------------------------------------
// Kernel 6c: fixup — add prev-group inclusive total into every chunk carry
// ---------------------------------------------------------------------------
__global__ void k_carryC(float* __restrict__ carR, float* __restrict__ carI,
                         const float* __restrict__ apgR, const float* __restrict__ apgI,
                         const float* __restrict__ gcarR, const float* __restrict__ gcarI)
{
    int gid = blockIdx.x * 256 + threadIdx.x;   // BSZ*NCH*DDIM
    int d = gid & 511, c = (gid >> 9) & 255, b = gid >> 17;
    int cg = c >> 4;
    if (cg == 0) return;
    int jj = c & 15;
    float fr = apgR[(jj+1)*DDIM + d], fi = apgI[(jj+1)*DDIM + d];
    size_t gidx = ((size_t)(b*NGRP + cg - 1))*DDIM + d;
    float gr = gcarR[gidx], gi = gcarI[gidx];
    size_t idx = ((size_t)(b * NCH + c)) * DDIM + d;
    carR[idx] += fr*gr - fi*gi;
    carI[idx] += fr*gi + fi*gr;
}

// ---------------------------------------------------------------------------
// Kernel 7: carry fixup + projection + band mixing + output — 4 ROWS/BLOCK.
// Rows t0..t0+3 share (b, chunk) so one carry row serves all 4; all block
// barriers are amortized 4x. grid = MROWS/4 = 4096, 512 threads.
// ---------------------------------------------------------------------------
__launch_bounds__(512)
__global__ void k_out(const float* __restrict__ HR, const float* __restrict__ HI,
                      const float* __restrict__ phR, const float* __restrict__ phI,
                      const float* __restrict__ carR, const float* __restrict__ carI,
                      const float* __restrict__ apR, const float* __restrict__ apI,
                      const int* __restrict__ bandOf, const int* __restrict__ posOf,
                      const float* __restrict__ tau, const float* __restrict__ beta,
                      float* __restrict__ out)
{
    __shared__ float sA[4][512], sB[4][512], sC[4][512];
    __shared__ float pA[4][8], pB[4][8], pC[4][8];
    __shared__ float red[8][8];

    int bt0 = blockIdx.x * 4;
    int b = bt0 >> 12, t0 = bt0 & 4095;
    int d = threadIdx.x;
    int w = d >> 6, lane = d & 63;
    int c = t0 >> 4, off0 = t0 & 15;            // rows t0..t0+3 in same chunk

    float hr[4], hi[4];
#pragma unroll
    for (int r = 0; r < 4; ++r) {
        size_t idx = ((size_t)(bt0 + r) << 9) + d;
        hr[r] = HR[idx]; hi[r] = HI[idx];
    }
    if (c > 0) {
        size_t ci = ((size_t)(b * NCH + (c - 1))) * DDIM + d;
        float cr = carR[ci], cm = carI[ci];
#pragma unroll
        for (int r = 0; r < 4; ++r) {
            float pr = apR[(off0 + r + 1) * DDIM + d];
            float pi = apI[(off0 + r + 1) * DDIM + d];
            hr[r] += pr*cr - pi*cm;
            hi[r] += pr*cm + pi*cr;
        }
    }

    // ---- mean over d (4 rows at once) ----
    float sh[4], si[4];
#pragma unroll
    for (int r = 0; r < 4; ++r) { sh[r] = hr[r]; si[r] = hi[r]; }
#pragma unroll
    for (int m = 32; m; m >>= 1)
#pragma unroll
        for (int r = 0; r < 4; ++r) { sh[r] += __shfl_xor(sh[r], m); si[r] += __shfl_xor(si[r], m); }
    if (lane == 0)
#pragma unroll
        for (int r = 0; r < 4; ++r) { red[w][2*r] = sh[r]; red[w][2*r+1] = si[r]; }
    __syncthreads();
    float mr[4], mi[4];
#pragma unroll
    for (int r = 0; r < 4; ++r) {
        float a = 0.f, bb = 0.f;
#pragma unroll
        for (int ww = 0; ww < 8; ++ww) { a += red[ww][2*r]; bb += red[ww][2*r+1]; }
        mr[r] = a * (1.f/512.f); mi[r] = bb * (1.f/512.f);
    }
    __syncthreads();

    // ---- var over d ----
    float dr[4], di[4];
#pragma unroll
    for (int r = 0; r < 4; ++r) {
        dr[r] = hr[r] - mr[r]; di[r] = hi[r] - mi[r];
        sh[r] = dr[r]*dr[r];   si[r] = di[r]*di[r];
    }
#pragma unroll
    for (int m = 32; m; m >>= 1)
#pragma unroll
        for (int r = 0; r < 4; ++r) { sh[r] += __shfl_xor(sh[r], m); si[r] += __shfl_xor(si[r], m); }
    if (lane == 0)
#pragma unroll
        for (int r = 0; r < 4; ++r) { red[w][2*r] = sh[r]; red[w][2*r+1] = si[r]; }
    __syncthreads();
    float Hpr[4], Hpi[4];
#pragma unroll
    for (int r = 0; r < 4; ++r) {
        float a = 0.f, bb = 0.f;
#pragma unroll
        for (int ww = 0; ww < 8; ++ww) { a += red[ww][2*r]; bb += red[ww][2*r+1]; }
        Hpr[r] = dr[r] / (sqrtf(a * (1.f/512.f)) + 1e-6f);
        Hpi[r] = di[r] / (sqrtf(bb * (1.f/512.f)) + 1e-6f);
    }
    __syncthreads();

    // ---- conj(H)*phi, density, scatter to band order ----
    int kb = bandOf[d], jb = posOf[d];
    int sidx = kb*128 + jb;
#pragma unroll
    for (int r = 0; r < 4; ++r) {
        size_t idx = ((size_t)(bt0 + r) << 9) + d;
        float pr_ = phR[idx], pi_ = phI[idx];
        sA[r][sidx] = Hpr[r]*pr_ + Hpi[r]*pi_;
        sB[r][sidx] = Hpr[r]*pi_ - Hpi[r]*pr_;
        sC[r][sidx] = Hpr[r]*Hpr[r] + Hpi[r]*Hpi[r];
    }
    __syncthreads();

    // ---- per-band partial sums (wave w covers half of band w/2) ----
#pragma unroll
    for (int r = 0; r < 4; ++r) {
        float v0 = sA[r][d], v1 = sB[r][d], v2 = sC[r][d];
#pragma unroll
        for (int m = 32; m; m >>= 1) {
            v0 += __shfl_xor(v0, m); v1 += __shfl_xor(v1, m); v2 += __shfl_xor(v2, m);
        }
        if (lane == 0) { pA[r][w] = v0; pB[r][w] = v1; pC[r][w] = v2; }
    }
    __syncthreads();

    // ---- softmax over K=4 bands (redundant per thread) + output ----
    float tv = tau[0]; tv = (tv < 1e-4f) ? 1e-4f : tv;
    float bt_s = beta[0];
#pragma unroll
    for (int r = 0; r < 4; ++r) {
        float aRk[4], aIk[4], dnk[4], mag[4];
        float mx = -1e30f;
#pragma unroll
        for (int k = 0; k < 4; k++) {
            aRk[k] = (pA[r][2*k] + pA[r][2*k+1]) * (1.f/128.f);
            aIk[k] = (pB[r][2*k] + pB[r][2*k+1]) * (1.f/128.f);
            dnk[k] = (pC[r][2*k] + pC[r][2*k+1]) * (1.f/128.f);
            mag[k] = sqrtf(aRk[k]*aRk[k] + aIk[k]*aIk[k]) / tv;
            mx = fmaxf(mx, mag[k]);
        }
        float se = 0.f, ek[4];
#pragma unroll
        for (int k = 0; k < 4; k++) { ek[k] = expf(mag[k] - mx); se += ek[k]; }
        float inv = 1.f / se;
        float ck  = ek[kb] * inv;
        float afR = aRk[kb] * ck * 4.f + bt_s * dnk[kb];
        float afI = aIk[kb] * ck * 4.f;
        size_t idx = ((size_t)(bt0 + r) << 9) + d;
        out[idx] = Hpr[r] * afR - Hpi[r] * afI;
    }
}

// ---------------------------------------------------------------------------
extern "C" void kernel_launch(void* const* d_in, const int* in_sizes, int n_in,
                              void* d_out, int out_size, void* d_ws, size_t ws_size,
                              hipStream_t stream)
{
    const float* x        = (const float*)d_in[0];
    const float* z_prev   = (const float*)d_in[1];
    const float* W_psi    = (const float*)d_in[2];
    const float* b_psi    = (const float*)d_in[3];
    const float* W_phi    = (const float*)d_in[4];
    const float* b_phi    = (const float*)d_in[5];
    const float* W_gate   = (const float*)d_in[6];
    const float* b_gate   = (const float*)d_in[7];
    const float* omega    = (const float*)d_in[8];
    const float* log_gam  = (const float*)d_in[9];
    const float* dt       = (const float*)d_in[10];
    const float* sg       = (const float*)d_in[11];
    const float* tau      = (const float*)d_in[12];
    const float* beta     = (const float*)d_in[13];
    const float* B_vec    = (const float*)d_in[14];
    const int*   band_idx = (const int*)d_in[15];
    float* out = (float*)d_out;
    float* ws  = (float*)d_ws;

    // workspace layout (floats)
    float* psiR = ws;                    // BLD  -> becomes H_re after scan
    float* psiI = psiR + BLD;            // BLD  -> becomes H_im
    float* phiR = psiI + BLD;            // BLD
    float* phiI = phiR + BLD;            // BLD
    float* gate = phiI + BLD;            // MROWS
    float* apR  = gate + MROWS;          // TBL
    float* apI  = apR + TBL;             // TBL
    float* apgR = apI + TBL;             // TBL
    float* apgI = apgR + TBL;            // TBL
    float* carR = apgI + TBL;            // BSZ*NCH*DDIM
    float* carI = carR + (size_t)BSZ*NCH*DDIM;
    float* gcarR = carI + (size_t)BSZ*NCH*DDIM;   // BSZ*NGRP*DDIM
    float* gcarI = gcarR + (size_t)BSZ*NGRP*DDIM;
    int* bandOf = (int*)(gcarI + (size_t)BSZ*NGRP*DDIM);  // DDIM
    int* posOf  = bandOf + DDIM;                          // DDIM
    unsigned short* Bhi = (unsigned short*)(posOf + DDIM);   // NCOLS*512 bf16
    unsigned short* Blo = Bhi + (size_t)NCOLS*512;           // NCOLS*512 bf16

    // A-operand bf16 planes live in d_out (dead until k_out writes it)
    unsigned short* Ahi = (unsigned short*)d_out;
    unsigned short* Alo = Ahi + (size_t)MROWS*512;

    k_prep<<<(2*TBL + 255)/256, 256, 0, stream>>>(
        omega, log_gam, dt, band_idx, apR, apI, apgR, apgI, bandOf, posOf);

    k_cvtgate<<<MROWS/4, 256, 0, stream>>>(x, z_prev, W_gate, b_gate, sg,
                                           gate, Ahi, Alo);

    k_cvtB<<<(NCOLS*64)/256, 256, 0, stream>>>(W_psi, W_phi, Bhi, Blo);

    k_gemm_bf16<<<(MROWS/128) * (NCOLS/128), 256, 0, stream>>>(
        Ahi, Alo, Bhi, Blo, b_psi, b_phi, psiR, psiI, phiR, phiI);

    k_scan<<<BSZ * NCH, 512, 0, stream>>>(psiR, psiI, gate, B_vec, apR, apI, carR, carI);

    k_carryA<<<(BSZ*NGRP*DDIM)/256, 256, 0, stream>>>(carR, carI, apR, apI);
    k_carryB<<<(BSZ*DDIM)/256, 256, 0, stream>>>(carR, carI, apgR, apgI, gcarR, gcarI);
    k_carryC<<<(BSZ*NCH*DDIM)/256, 256, 0, stream>>>(carR, carI, apgR, apgI, gcarR, gcarI);

    k_out<<<MROWS/4, 512, 0, stream>>>(psiR, psiI, phiR, phiI, carR, carI,
                                       apR, apI, bandOf, posOf, tau, beta, out);
}